// Round 1
// baseline (2314.727 us; speedup 1.0000x reference)
//
#include <hip/hip_runtime.h>

#define NPTS 4096
#define NB 8
#define NSEG 4          // partial-sum segments for the reduced axis
#define TPB 256
#define CHUNK 1024      // NPTS / NSEG
#define EPSC 1e-9f
#define SKIP_THRESH -126.0f

#if __has_builtin(__builtin_amdgcn_exp2f)
#define EXP2(x) __builtin_amdgcn_exp2f(x)
#else
#define EXP2(x) exp2f(x)
#endif

// ---------------------------------------------------------------------------
// CA kernel: fuses pass C of iteration `iter` (rsum[n] = sum_m e_cur*u[m])
// with pass A of iteration iter+1 (denom[n] = sum_m e_next*remainR_next[m]).
// MODE 0: first call (A_0 only, iter=-1). MODE 1: middle (e_cur = e_next^4).
// MODE 2: last (iter=8; level_next = 0 so denom += rr; e_cur computed directly).
// Grid: (nchunk=16, mseg=4, b=8), 256 threads, thread owns one n, loops 1024 m.
// ---------------------------------------------------------------------------
template<int MODE>
__global__ __launch_bounds__(TPB) void ca_kernel(
    const float* __restrict__ x1, const float* __restrict__ x2,
    float* __restrict__ dbuf,          // [2][NSEG][NB][NPTS] denom partials
    float* __restrict__ rsumP,         // [NSEG][NB][NPTS]
    const float* __restrict__ s0P,     // [NSEG][NB][NPTS]
    const float* __restrict__ s1P,     // [NSEG][NB][NPTS]
    float* __restrict__ rrbuf,         // [2][NB][NPTS]
    float* __restrict__ costbuf,       // [NB]
    int iter, float c2cur, float c2next)
{
  __shared__ float4 x2s[CHUNK];   // (x,y,z,u)
  __shared__ float  rrs[CHUNK];   // remainR_next
  __shared__ float  red[TPB];

  const int tid    = threadIdx.x;
  const int nchunk = blockIdx.x;
  const int mseg   = blockIdx.y;
  const int b      = blockIdx.z;
  const int m0     = mseg * CHUNK;

  float cpart = 0.f;
  for (int t = 0; t < CHUNK / TPB; ++t) {
    int mm = tid + t * TPB;
    int m  = m0 + mm;
    const float* q = x2 + ((size_t)b * NPTS + m) * 3;
    float qx = q[0], qy = q[1], qz = q[2];
    float u = 0.f, rrn = 1.f;
    if (MODE >= 1) {
      float s0 = 0.f;
#pragma unroll
      for (int s = 0; s < NSEG; ++s) s0 += s0P[(s * NB + b) * NPTS + m];
      float rr    = (iter == 0) ? 1.f : rrbuf[(iter & 1) * NB * NPTS + b * NPTS + m];
      float sumr  = rr * s0 + EPSC;
      float ratio = fminf(rr / sumr, 1.f);
      u   = rr * ratio;
      rrn = fmaxf(rr - u * s0, 0.f);
      if (nchunk == 0) {
        rrbuf[((iter + 1) & 1) * NB * NPTS + b * NPTS + m] = rrn;
        float s1 = 0.f;
#pragma unroll
        for (int s = 0; s < NSEG; ++s) s1 += s1P[(s * NB + b) * NPTS + m];
        cpart += u * s1;
      }
    } else {
      if (nchunk == 0 && mseg == 0 && mm == 0) costbuf[b] = 0.f;
    }
    x2s[mm] = make_float4(qx, qy, qz, u);
    rrs[mm] = rrn;
  }
  if (MODE >= 1 && nchunk == 0) {
    red[tid] = cpart;
    __syncthreads();
    for (int s = TPB / 2; s > 0; s >>= 1) {
      if (tid < s) red[tid] += red[tid + s];
      __syncthreads();
    }
    if (tid == 0) atomicAdd(costbuf + b, red[0]);
  }
  __syncthreads();

  const int n = nchunk * TPB + tid;
  const float* p = x1 + ((size_t)b * NPTS + n) * 3;
  float px = p[0], py = p[1], pz = p[2];
  float dacc = 0.f, racc = 0.f;

#pragma unroll 4
  for (int mm = 0; mm < CHUNK; ++mm) {
    float4 q  = x2s[mm];
    float dx = px - q.x, dy = py - q.y, dz = pz - q.z;
    float d2 = fmaf(dz, dz, fmaf(dy, dy, dx * dx));
    if (MODE <= 1) {
      float argn = d2 * c2next;
      if (argn > SKIP_THRESH) {
        float en = EXP2(argn);
        dacc = fmaf(en, rrs[mm], dacc);
        if (MODE == 1) {
          float e2 = en * en;
          float e4 = e2 * e2;            // e_cur = e_next^4 (level_cur = 4*level_next)
          racc = fmaf(e4, q.w, racc);
        }
      }
    } else {  // MODE 2: level_next == 0 -> e_next = 1
      dacc += rrs[mm];
      float argc = d2 * c2cur;
      if (argc > SKIP_THRESH) {
        float ec = EXP2(argc);
        racc = fmaf(ec, q.w, racc);
      }
    }
  }

  dbuf[((((iter + 1) & 1) * NSEG + mseg) * NB + b) * NPTS + n] = dacc;
  if (MODE >= 1) rsumP[(mseg * NB + b) * NPTS + n] = racc;
}

// ---------------------------------------------------------------------------
// B kernel: pass B of iteration `iter`. Thread owns one m, loops 1024 n.
// Prologue recomputes remainL_iter (from remainL_{iter-1}, a_{iter-1}, rsum)
// and a_iter[n]; mchunk==0 blocks persist remainL_iter to lbuf.
// Grid: (mchunk=16, nseg=4, b=8).
// ---------------------------------------------------------------------------
__global__ __launch_bounds__(TPB) void b_kernel(
    const float* __restrict__ x1, const float* __restrict__ x2,
    const float* __restrict__ dbuf,
    const float* __restrict__ rsumP,
    float* __restrict__ s0P, float* __restrict__ s1P,
    float* __restrict__ lbuf,          // [2][NB][NPTS]
    int iter, float c2)
{
  __shared__ float4 x1s[CHUNK];   // (x,y,z,a)

  const int tid    = threadIdx.x;
  const int mchunk = blockIdx.x;
  const int nseg   = blockIdx.y;
  const int b      = blockIdx.z;
  const int n0     = nseg * CHUNK;

  for (int t = 0; t < CHUNK / TPB; ++t) {
    int nn = tid + t * TPB;
    int n  = n0 + nn;
    float dsum = 0.f;
#pragma unroll
    for (int s = 0; s < NSEG; ++s)
      dsum += dbuf[(((iter & 1) * NSEG + s) * NB + b) * NPTS + n];
    float rl;
    if (iter == 0) {
      rl = 1.f;
    } else {
      float rlp = lbuf[((iter - 1) & 1) * NB * NPTS + b * NPTS + n];
      float dprev = 0.f;
#pragma unroll
      for (int s = 0; s < NSEG; ++s)
        dprev += dbuf[((((iter - 1) & 1) * NSEG + s) * NB + b) * NPTS + n];
      float ap = rlp / (dprev + EPSC);
      float rs = 0.f;
#pragma unroll
      for (int s = 0; s < NSEG; ++s) rs += rsumP[(s * NB + b) * NPTS + n];
      rl = fmaxf(rlp - ap * rs, 0.f);
    }
    if (mchunk == 0) lbuf[(iter & 1) * NB * NPTS + b * NPTS + n] = rl;
    float a = rl / (dsum + EPSC);
    const float* p = x1 + ((size_t)b * NPTS + n) * 3;
    x1s[nn] = make_float4(p[0], p[1], p[2], a);
  }
  __syncthreads();

  const int m = mchunk * TPB + tid;
  const float* q = x2 + ((size_t)b * NPTS + m) * 3;
  float qx = q[0], qy = q[1], qz = q[2];
  float s0a = 0.f, s1a = 0.f;

#pragma unroll 4
  for (int nn = 0; nn < CHUNK; ++nn) {
    float4 p  = x1s[nn];
    float dx = p.x - qx, dy = p.y - qy, dz = p.z - qz;
    float d2 = fmaf(dz, dz, fmaf(dy, dy, dx * dx));
    float arg = d2 * c2;
    if (arg > SKIP_THRESH) {
      float e  = EXP2(arg);
      float tt = p.w * e;
      s0a += tt;
      float dist = sqrtf(fmaxf(d2, 1e-12f));
      s1a = fmaf(tt, dist, s1a);
    }
  }

  s0P[(nseg * NB + b) * NPTS + m] = s0a;
  s1P[(nseg * NB + b) * NPTS + m] = s1a;
}

// ---------------------------------------------------------------------------
// F kernel: final iteration's cost contribution (u_9 from s0P_9, remainR_9)
// plus the accumulated costbuf. One block per batch.
// ---------------------------------------------------------------------------
__global__ __launch_bounds__(TPB) void f_kernel(
    const float* __restrict__ s0P, const float* __restrict__ s1P,
    const float* __restrict__ rrbuf, const float* __restrict__ costbuf,
    float* __restrict__ out)
{
  __shared__ float red[TPB];
  const int b   = blockIdx.x;
  const int tid = threadIdx.x;
  float acc = 0.f;
  for (int m = tid; m < NPTS; m += TPB) {
    float s0 = 0.f, s1 = 0.f;
#pragma unroll
    for (int s = 0; s < NSEG; ++s) {
      s0 += s0P[(s * NB + b) * NPTS + m];
      s1 += s1P[(s * NB + b) * NPTS + m];
    }
    float rr    = rrbuf[1 * NB * NPTS + b * NPTS + m];  // remainR_9 (parity 9&1=1)
    float sumr  = rr * s0 + EPSC;
    float ratio = fminf(rr / sumr, 1.f);
    acc = fmaf(rr * ratio, s1, acc);
  }
  red[tid] = acc;
  __syncthreads();
  for (int s = TPB / 2; s > 0; s >>= 1) {
    if (tid < s) red[tid] += red[tid + s];
    __syncthreads();
  }
  if (tid == 0) out[b] = costbuf[b] + red[0];
}

extern "C" void kernel_launch(void* const* d_in, const int* in_sizes, int n_in,
                              void* d_out, int out_size, void* d_ws, size_t ws_size,
                              hipStream_t stream) {
  const float* x1 = (const float*)d_in[0];
  const float* x2 = (const float*)d_in[1];
  float* out = (float*)d_out;

  float* ws      = (float*)d_ws;
  float* dbuf    = ws;                                  // 2*NSEG*NB*NPTS
  float* rsumP   = dbuf  + 2 * NSEG * NB * NPTS;        // NSEG*NB*NPTS
  float* s0P     = rsumP + NSEG * NB * NPTS;
  float* s1P     = s0P   + NSEG * NB * NPTS;
  float* lbuf    = s1P   + NSEG * NB * NPTS;            // 2*NB*NPTS
  float* rrbuf   = lbuf  + 2 * NB * NPTS;               // 2*NB*NPTS
  float* costbuf = rrbuf + 2 * NB * NPTS;               // NB

  const double L2E = 1.4426950408889634074;
  const double lv[10] = {-16384.0, -4096.0, -1024.0, -256.0, -64.0,
                         -16.0, -4.0, -1.0, -0.25, 0.0};
  float c2[10];
  for (int i = 0; i < 10; ++i) c2[i] = (float)(lv[i] * L2E);

  dim3 grid(16, NSEG, NB), blk(TPB);

  // A_0 (denom_0 partials), zero costbuf
  ca_kernel<0><<<grid, blk, 0, stream>>>(x1, x2, dbuf, rsumP, s0P, s1P,
                                         rrbuf, costbuf, -1, 0.f, c2[0]);
  for (int i = 0; i < 10; ++i) {
    b_kernel<<<grid, blk, 0, stream>>>(x1, x2, dbuf, rsumP, s0P, s1P,
                                       lbuf, i, c2[i]);
    if (i < 8) {
      ca_kernel<1><<<grid, blk, 0, stream>>>(x1, x2, dbuf, rsumP, s0P, s1P,
                                             rrbuf, costbuf, i, c2[i], c2[i + 1]);
    } else if (i == 8) {
      ca_kernel<2><<<grid, blk, 0, stream>>>(x1, x2, dbuf, rsumP, s0P, s1P,
                                             rrbuf, costbuf, 8, c2[8], 0.f);
    }
  }
  f_kernel<<<dim3(NB), blk, 0, stream>>>(s0P, s1P, rrbuf, costbuf, out);
}

// Round 2
// 1284.518 us; speedup vs baseline: 1.8020x; 1.8020x over previous
//
#include <hip/hip_runtime.h>

#define NPTS 4096
#define NB 8
#define TPB 256
#define MBLK 2          // points of the owned axis per thread
#define MAXCHUNK 1024   // worst-case chunk (nseg=4 fallback)
#define EPSC 1e-9f

#define EXP2(x)  __builtin_amdgcn_exp2f(x)
#define RCPF(x)  __builtin_amdgcn_rcpf(x)
#define SQRTF(x) __builtin_amdgcn_sqrtf(x)

// ---------------------------------------------------------------------------
// CA kernel: fuses pass C of iteration `iter` (rsum[n] = sum_m e_cur*u[m])
// with pass A of iteration iter+1 (denom[n] = sum_m e_next*remainR_next[m]).
// MODE 0: first call (A_0 only). MODE 1: middle (e_cur = e_next^4).
// MODE 2: last (iter=8; level_next = 0 -> denom += rr).
// SKIP: whole-wave skip branch when exp2 arg underflows (early levels only).
// Thread owns MBLK n's (stride TPB); loops `chunk` m's staged in LDS.
// ---------------------------------------------------------------------------
template<int MODE, bool SKIP>
__global__ __launch_bounds__(TPB) void ca_kernel(
    const float* __restrict__ x1, const float* __restrict__ x2,
    float* __restrict__ dbuf,          // [2][nseg][NB][NPTS] denom partials
    float* __restrict__ rsumP,         // [nseg][NB][NPTS]
    const float* __restrict__ s0P,     // [nseg][NB][NPTS]
    const float* __restrict__ s1P,     // [nseg][NB][NPTS]
    float* __restrict__ rrbuf,         // [2][NB][NPTS]
    float* __restrict__ costbuf,       // [NB]
    int iter, float c2cur, float c2next, int nseg, int chunk)
{
  __shared__ float4 x2s[MAXCHUNK];   // (x,y,z,u)
  __shared__ float  rrs[MAXCHUNK];   // remainR_next
  __shared__ float  red[TPB];

  const int tid    = threadIdx.x;
  const int nchunk = blockIdx.x;
  const int mseg   = blockIdx.y;
  const int b      = blockIdx.z;
  const int m0     = mseg * chunk;
  const int plane  = NB * NPTS;

  float cpart = 0.f;
  for (int mm = tid; mm < chunk; mm += TPB) {
    int m = m0 + mm;
    const float* q = x2 + ((size_t)b * NPTS + m) * 3;
    float qx = q[0], qy = q[1], qz = q[2];
    float u = 0.f, rrn = 1.f;
    if (MODE >= 1) {
      float s0 = 0.f;
      for (int s = 0; s < nseg; ++s) s0 += s0P[(s * NB + b) * NPTS + m];
      float rr    = (iter == 0) ? 1.f : rrbuf[(iter & 1) * plane + b * NPTS + m];
      float sumr  = fmaf(rr, s0, EPSC);
      float ratio = fminf(rr * RCPF(sumr), 1.f);
      u   = rr * ratio;
      rrn = fmaxf(rr - u * s0, 0.f);
      if (nchunk == 0) {
        rrbuf[((iter + 1) & 1) * plane + b * NPTS + m] = rrn;
        float s1 = 0.f;
        for (int s = 0; s < nseg; ++s) s1 += s1P[(s * NB + b) * NPTS + m];
        cpart += u * s1;
      }
    } else {
      if (nchunk == 0 && mseg == 0 && mm == 0) costbuf[b] = 0.f;
    }
    x2s[mm] = make_float4(qx, qy, qz, u);
    rrs[mm] = rrn;
  }
  if (MODE >= 1 && nchunk == 0) {
    red[tid] = cpart;
    __syncthreads();
    for (int s = TPB / 2; s > 0; s >>= 1) {
      if (tid < s) red[tid] += red[tid + s];
      __syncthreads();
    }
    if (tid == 0) atomicAdd(costbuf + b, red[0]);
  }
  __syncthreads();

  const int n0 = nchunk * (TPB * MBLK) + tid;
  const int n1 = n0 + TPB;
  const float* p0 = x1 + ((size_t)b * NPTS + n0) * 3;
  const float* p1 = x1 + ((size_t)b * NPTS + n1) * 3;
  float px0 = p0[0], py0 = p0[1], pz0 = p0[2];
  float px1 = p1[0], py1 = p1[1], pz1 = p1[2];
  float dacc0 = 0.f, racc0 = 0.f, dacc1 = 0.f, racc1 = 0.f;

#pragma unroll 4
  for (int mm = 0; mm < chunk; ++mm) {
    float4 q  = x2s[mm];
    float rrv = rrs[mm];
    {
      float dx = px0 - q.x, dy = py0 - q.y, dz = pz0 - q.z;
      float d2 = fmaf(dz, dz, fmaf(dy, dy, dx * dx));
      if (MODE <= 1) {
        float argn = d2 * c2next;
        if (!SKIP || argn > -126.f) {
          float en = EXP2(argn);
          dacc0 = fmaf(en, rrv, dacc0);
          if (MODE == 1) { float e2 = en * en; racc0 = fmaf(e2 * e2, q.w, racc0); }
        }
      } else {
        dacc0 += rrv;
        float ec = EXP2(d2 * c2cur);
        racc0 = fmaf(ec, q.w, racc0);
      }
    }
    {
      float dx = px1 - q.x, dy = py1 - q.y, dz = pz1 - q.z;
      float d2 = fmaf(dz, dz, fmaf(dy, dy, dx * dx));
      if (MODE <= 1) {
        float argn = d2 * c2next;
        if (!SKIP || argn > -126.f) {
          float en = EXP2(argn);
          dacc1 = fmaf(en, rrv, dacc1);
          if (MODE == 1) { float e2 = en * en; racc1 = fmaf(e2 * e2, q.w, racc1); }
        }
      } else {
        dacc1 += rrv;
        float ec = EXP2(d2 * c2cur);
        racc1 = fmaf(ec, q.w, racc1);
      }
    }
  }

  size_t dbase = ((size_t)(((iter + 1) & 1) * nseg + mseg) * NB + b) * NPTS;
  dbuf[dbase + n0] = dacc0;
  dbuf[dbase + n1] = dacc1;
  if (MODE >= 1) {
    size_t rbase = ((size_t)mseg * NB + b) * NPTS;
    rsumP[rbase + n0] = racc0;
    rsumP[rbase + n1] = racc1;
  }
}

// ---------------------------------------------------------------------------
// B kernel: pass B of iteration `iter`: s0[m] = sum_n a*e, s1[m] = sum_n a*e*dist.
// Prologue recomputes remainL_iter and a_iter[n]; mchunk==0 persists remainL.
// Thread owns MBLK m's (stride TPB); loops `chunk` n's staged in LDS.
// ---------------------------------------------------------------------------
template<bool SKIP>
__global__ __launch_bounds__(TPB) void b_kernel(
    const float* __restrict__ x1, const float* __restrict__ x2,
    const float* __restrict__ dbuf,
    const float* __restrict__ rsumP,
    float* __restrict__ s0P, float* __restrict__ s1P,
    float* __restrict__ lbuf,          // [2][NB][NPTS]
    int iter, float c2, int nseg, int chunk)
{
  __shared__ float4 x1s[MAXCHUNK];   // (x,y,z,a)

  const int tid    = threadIdx.x;
  const int mchunk = blockIdx.x;
  const int nsegi  = blockIdx.y;
  const int b      = blockIdx.z;
  const int nb0    = nsegi * chunk;
  const int plane  = NB * NPTS;

  for (int nn = tid; nn < chunk; nn += TPB) {
    int n = nb0 + nn;
    float dsum = 0.f;
    for (int s = 0; s < nseg; ++s)
      dsum += dbuf[(((iter & 1) * nseg + s) * NB + b) * NPTS + n];
    float rl;
    if (iter == 0) {
      rl = 1.f;
    } else {
      float rlp = lbuf[((iter - 1) & 1) * plane + b * NPTS + n];
      float dprev = 0.f;
      for (int s = 0; s < nseg; ++s)
        dprev += dbuf[((((iter - 1) & 1) * nseg + s) * NB + b) * NPTS + n];
      float ap = rlp * RCPF(dprev + EPSC);
      float rs = 0.f;
      for (int s = 0; s < nseg; ++s) rs += rsumP[(s * NB + b) * NPTS + n];
      rl = fmaxf(rlp - ap * rs, 0.f);
    }
    if (mchunk == 0) lbuf[(iter & 1) * plane + b * NPTS + n] = rl;
    float a = rl * RCPF(dsum + EPSC);
    const float* p = x1 + ((size_t)b * NPTS + n) * 3;
    x1s[nn] = make_float4(p[0], p[1], p[2], a);
  }
  __syncthreads();

  const int m0 = mchunk * (TPB * MBLK) + tid;
  const int m1 = m0 + TPB;
  const float* q0 = x2 + ((size_t)b * NPTS + m0) * 3;
  const float* q1 = x2 + ((size_t)b * NPTS + m1) * 3;
  float qx0 = q0[0], qy0 = q0[1], qz0 = q0[2];
  float qx1 = q1[0], qy1 = q1[1], qz1 = q1[2];
  float s0a0 = 0.f, s1a0 = 0.f, s0a1 = 0.f, s1a1 = 0.f;

#pragma unroll 4
  for (int nn = 0; nn < chunk; ++nn) {
    float4 p = x1s[nn];
    {
      float dx = p.x - qx0, dy = p.y - qy0, dz = p.z - qz0;
      float d2 = fmaf(dz, dz, fmaf(dy, dy, dx * dx));
      float arg = d2 * c2;
      if (!SKIP || arg > -126.f) {
        float e  = EXP2(arg);
        float tt = p.w * e;
        s0a0 += tt;
        s1a0 = fmaf(tt, SQRTF(d2), s1a0);
      }
    }
    {
      float dx = p.x - qx1, dy = p.y - qy1, dz = p.z - qz1;
      float d2 = fmaf(dz, dz, fmaf(dy, dy, dx * dx));
      float arg = d2 * c2;
      if (!SKIP || arg > -126.f) {
        float e  = EXP2(arg);
        float tt = p.w * e;
        s0a1 += tt;
        s1a1 = fmaf(tt, SQRTF(d2), s1a1);
      }
    }
  }

  size_t sbase = ((size_t)nsegi * NB + b) * NPTS;
  s0P[sbase + m0] = s0a0;
  s0P[sbase + m1] = s0a1;
  s1P[sbase + m0] = s1a0;
  s1P[sbase + m1] = s1a1;
}

// ---------------------------------------------------------------------------
// F kernel: final iteration's cost contribution + accumulated costbuf.
// ---------------------------------------------------------------------------
__global__ __launch_bounds__(TPB) void f_kernel(
    const float* __restrict__ s0P, const float* __restrict__ s1P,
    const float* __restrict__ rrbuf, const float* __restrict__ costbuf,
    float* __restrict__ out, int nseg)
{
  __shared__ float red[TPB];
  const int b   = blockIdx.x;
  const int tid = threadIdx.x;
  const int plane = NB * NPTS;
  float acc = 0.f;
  for (int m = tid; m < NPTS; m += TPB) {
    float s0 = 0.f, s1 = 0.f;
    for (int s = 0; s < nseg; ++s) {
      s0 += s0P[(s * NB + b) * NPTS + m];
      s1 += s1P[(s * NB + b) * NPTS + m];
    }
    float rr    = rrbuf[1 * plane + b * NPTS + m];  // remainR_9 (parity 9&1=1)
    float sumr  = fmaf(rr, s0, EPSC);
    float ratio = fminf(rr * RCPF(sumr), 1.f);
    acc = fmaf(rr * ratio, s1, acc);
  }
  red[tid] = acc;
  __syncthreads();
  for (int s = TPB / 2; s > 0; s >>= 1) {
    if (tid < s) red[tid] += red[tid + s];
    __syncthreads();
  }
  if (tid == 0) out[b] = costbuf[b] + red[0];
}

extern "C" void kernel_launch(void* const* d_in, const int* in_sizes, int n_in,
                              void* d_out, int out_size, void* d_ws, size_t ws_size,
                              hipStream_t stream) {
  const float* x1 = (const float*)d_in[0];
  const float* x2 = (const float*)d_in[1];
  float* out = (float*)d_out;

  const size_t plane = (size_t)NB * NPTS;
  // ws need: dbuf 2*nseg + rsum/s0/s1 nseg each = 5*nseg planes, + lbuf 2 + rrbuf 2 + costbuf
  int nseg = 16;
  while (nseg > 4 &&
         ((size_t)(5 * nseg + 4) * plane + NB) * sizeof(float) > ws_size)
    nseg >>= 1;
  const int chunk = NPTS / nseg;

  float* ws      = (float*)d_ws;
  float* dbuf    = ws;
  float* rsumP   = dbuf  + 2 * nseg * plane;
  float* s0P     = rsumP + nseg * plane;
  float* s1P     = s0P   + nseg * plane;
  float* lbuf    = s1P   + nseg * plane;
  float* rrbuf   = lbuf  + 2 * plane;
  float* costbuf = rrbuf + 2 * plane;

  const double L2E = 1.4426950408889634074;
  const double lv[10] = {-16384.0, -4096.0, -1024.0, -256.0, -64.0,
                         -16.0, -4.0, -1.0, -0.25, 0.0};
  float c2[10];
  for (int i = 0; i < 10; ++i) c2[i] = (float)(lv[i] * L2E);

  dim3 grid(NPTS / (TPB * MBLK), nseg, NB), blk(TPB);

  // A_0 (denom_0 partials), zero costbuf
  ca_kernel<0, true><<<grid, blk, 0, stream>>>(
      x1, x2, dbuf, rsumP, s0P, s1P, rrbuf, costbuf, -1, 0.f, c2[0], nseg, chunk);
  for (int i = 0; i < 10; ++i) {
    if (i <= 5)
      b_kernel<true><<<grid, blk, 0, stream>>>(
          x1, x2, dbuf, rsumP, s0P, s1P, lbuf, i, c2[i], nseg, chunk);
    else
      b_kernel<false><<<grid, blk, 0, stream>>>(
          x1, x2, dbuf, rsumP, s0P, s1P, lbuf, i, c2[i], nseg, chunk);
    if (i < 8) {
      if (i <= 4)
        ca_kernel<1, true><<<grid, blk, 0, stream>>>(
            x1, x2, dbuf, rsumP, s0P, s1P, rrbuf, costbuf, i, c2[i], c2[i + 1], nseg, chunk);
      else
        ca_kernel<1, false><<<grid, blk, 0, stream>>>(
            x1, x2, dbuf, rsumP, s0P, s1P, rrbuf, costbuf, i, c2[i], c2[i + 1], nseg, chunk);
    } else if (i == 8) {
      ca_kernel<2, false><<<grid, blk, 0, stream>>>(
          x1, x2, dbuf, rsumP, s0P, s1P, rrbuf, costbuf, 8, c2[8], 0.f, nseg, chunk);
    }
  }
  f_kernel<<<dim3(NB), blk, 0, stream>>>(s0P, s1P, rrbuf, costbuf, out, nseg);
}

// Round 4
// 1221.578 us; speedup vs baseline: 1.8949x; 1.0515x over previous
//
#include <hip/hip_runtime.h>

#define NPTS 4096
#define NB 8
#define TPB 256
#define MBLK 4          // points of the owned axis per thread (indep acc chains)
#define MAXCHUNK 1024   // worst-case chunk (nseg=4 fallback)
#define EPSC 1e-9f

#define EXP2(x)  __builtin_amdgcn_exp2f(x)
#define RCPF(x)  __builtin_amdgcn_rcpf(x)
#define SQRTF(x) __builtin_amdgcn_sqrtf(x)

// ---------------------------------------------------------------------------
// CA kernel: fuses pass C of iteration `iter` (rsum[n] = sum_m e_cur*u[m])
// with pass A of iteration iter+1 (denom[n] = sum_m e_next*remainR_next[m]).
// MODE 0: first call (A_0 only). MODE 1: middle (e_cur = e_next^4).
// MODE 2: last (iter=8; level_next = 0 -> denom += rr).
// SKIP: group skip branch (4 pairs x 64 lanes) when exp2 arg underflows --
// only for the earliest levels where whole-wave skip actually fires.
// Thread owns MBLK n's (stride TPB); loops `chunk` m's staged in LDS.
// ---------------------------------------------------------------------------
template<int MODE, bool SKIP>
__global__ __launch_bounds__(TPB) void ca_kernel(
    const float* __restrict__ x1, const float* __restrict__ x2,
    float* __restrict__ dbuf,          // [2][nseg][NB][NPTS] denom partials
    float* __restrict__ rsumP,         // [nseg][NB][NPTS]
    const float* __restrict__ s0P,     // [nseg][NB][NPTS]
    const float* __restrict__ s1P,     // [nseg][NB][NPTS]
    float* __restrict__ rrbuf,         // [2][NB][NPTS]
    float* __restrict__ costbuf,       // [NB]
    int iter, float c2cur, float c2next, int nseg, int chunk)
{
  __shared__ float4 x2s[MAXCHUNK];   // (x,y,z,u)
  __shared__ float  rrs[MAXCHUNK];   // remainR_next
  __shared__ float  red[TPB];

  const int tid    = threadIdx.x;
  const int nchunk = blockIdx.x;
  const int mseg   = blockIdx.y;
  const int b      = blockIdx.z;
  const int m0     = mseg * chunk;
  const int plane  = NB * NPTS;

  float cpart = 0.f;
  for (int mm = tid; mm < chunk; mm += TPB) {
    int m = m0 + mm;
    const float* q = x2 + ((size_t)b * NPTS + m) * 3;
    float qx = q[0], qy = q[1], qz = q[2];
    float u = 0.f, rrn = 1.f;
    if (MODE >= 1) {
      float s0 = 0.f;
      for (int s = 0; s < nseg; ++s) s0 += s0P[(s * NB + b) * NPTS + m];
      float rr    = (iter == 0) ? 1.f : rrbuf[(iter & 1) * plane + b * NPTS + m];
      float sumr  = fmaf(rr, s0, EPSC);
      float ratio = fminf(rr * RCPF(sumr), 1.f);
      u   = rr * ratio;
      rrn = fmaxf(rr - u * s0, 0.f);
      if (nchunk == 0) {
        rrbuf[((iter + 1) & 1) * plane + b * NPTS + m] = rrn;
        float s1 = 0.f;
        for (int s = 0; s < nseg; ++s) s1 += s1P[(s * NB + b) * NPTS + m];
        cpart += u * s1;
      }
    } else {
      if (nchunk == 0 && mseg == 0 && mm == 0) costbuf[b] = 0.f;
    }
    x2s[mm] = make_float4(qx, qy, qz, u);
    rrs[mm] = rrn;
  }
  if (MODE >= 1 && nchunk == 0) {
    red[tid] = cpart;
    __syncthreads();
    for (int s = TPB / 2; s > 0; s >>= 1) {
      if (tid < s) red[tid] += red[tid + s];
      __syncthreads();
    }
    if (tid == 0) atomicAdd(costbuf + b, red[0]);
  }
  __syncthreads();

  const int n0 = nchunk * (TPB * MBLK) + tid;
  float px[MBLK], py[MBLK], pz[MBLK], dacc[MBLK], racc[MBLK];
#pragma unroll
  for (int k = 0; k < MBLK; ++k) {
    const float* p = x1 + ((size_t)b * NPTS + n0 + k * TPB) * 3;
    px[k] = p[0]; py[k] = p[1]; pz[k] = p[2];
    dacc[k] = 0.f; racc[k] = 0.f;
  }

#pragma unroll 2
  for (int mm = 0; mm < chunk; ++mm) {
    float4 q  = x2s[mm];
    float rrv = rrs[mm];
    float argn[MBLK];
#pragma unroll
    for (int k = 0; k < MBLK; ++k) {
      float dx = px[k] - q.x, dy = py[k] - q.y, dz = pz[k] - q.z;
      float d2 = fmaf(dz, dz, fmaf(dy, dy, dx * dx));
      argn[k] = d2 * (MODE == 2 ? c2cur : c2next);
    }
    if (MODE <= 1) {
      bool go = true;
      if (SKIP) {
        float amax = argn[0];
#pragma unroll
        for (int k = 1; k < MBLK; ++k) amax = fmaxf(amax, argn[k]);
        go = amax > -126.f;
      }
      if (go) {
#pragma unroll
        for (int k = 0; k < MBLK; ++k) {
          float en = EXP2(argn[k]);
          dacc[k] = fmaf(en, rrv, dacc[k]);
          if (MODE == 1) { float e2 = en * en; racc[k] = fmaf(e2 * e2, q.w, racc[k]); }
        }
      }
    } else {  // MODE 2: level_next == 0 -> e_next = 1
#pragma unroll
      for (int k = 0; k < MBLK; ++k) {
        dacc[k] += rrv;
        float ec = EXP2(argn[k]);
        racc[k] = fmaf(ec, q.w, racc[k]);
      }
    }
  }

  size_t dbase = ((size_t)(((iter + 1) & 1) * nseg + mseg) * NB + b) * NPTS;
  size_t rbase = ((size_t)mseg * NB + b) * NPTS;
#pragma unroll
  for (int k = 0; k < MBLK; ++k) {
    dbuf[dbase + n0 + k * TPB] = dacc[k];
    if (MODE >= 1) rsumP[rbase + n0 + k * TPB] = racc[k];
  }
}

// ---------------------------------------------------------------------------
// B kernel: pass B of iteration `iter`: s0[m] = sum_n a*e, s1[m] = sum_n a*e*dist.
// Prologue recomputes remainL_iter and a_iter[n]; mchunk==0 persists remainL.
// Thread owns MBLK m's (stride TPB); loops `chunk` n's staged in LDS.
// ---------------------------------------------------------------------------
template<bool SKIP>
__global__ __launch_bounds__(TPB) void b_kernel(
    const float* __restrict__ x1, const float* __restrict__ x2,
    const float* __restrict__ dbuf,
    const float* __restrict__ rsumP,
    float* __restrict__ s0P, float* __restrict__ s1P,
    float* __restrict__ lbuf,          // [2][NB][NPTS]
    int iter, float c2, int nseg, int chunk)
{
  __shared__ float4 x1s[MAXCHUNK];   // (x,y,z,a)

  const int tid    = threadIdx.x;
  const int mchunk = blockIdx.x;
  const int nsegi  = blockIdx.y;
  const int b      = blockIdx.z;
  const int nb0    = nsegi * chunk;
  const int plane  = NB * NPTS;

  for (int nn = tid; nn < chunk; nn += TPB) {
    int n = nb0 + nn;
    float dsum = 0.f;
    for (int s = 0; s < nseg; ++s)
      dsum += dbuf[(((iter & 1) * nseg + s) * NB + b) * NPTS + n];
    float rl;
    if (iter == 0) {
      rl = 1.f;
    } else {
      float rlp = lbuf[((iter - 1) & 1) * plane + b * NPTS + n];
      float dprev = 0.f;
      for (int s = 0; s < nseg; ++s)
        dprev += dbuf[((((iter - 1) & 1) * nseg + s) * NB + b) * NPTS + n];
      float ap = rlp * RCPF(dprev + EPSC);
      float rs = 0.f;
      for (int s = 0; s < nseg; ++s) rs += rsumP[(s * NB + b) * NPTS + n];
      rl = fmaxf(rlp - ap * rs, 0.f);
    }
    if (mchunk == 0) lbuf[(iter & 1) * plane + b * NPTS + n] = rl;
    float a = rl * RCPF(dsum + EPSC);
    const float* p = x1 + ((size_t)b * NPTS + n) * 3;
    x1s[nn] = make_float4(p[0], p[1], p[2], a);
  }
  __syncthreads();

  const int m0 = mchunk * (TPB * MBLK) + tid;
  float qx[MBLK], qy[MBLK], qz[MBLK], s0a[MBLK], s1a[MBLK];
#pragma unroll
  for (int k = 0; k < MBLK; ++k) {
    const float* q = x2 + ((size_t)b * NPTS + m0 + k * TPB) * 3;
    qx[k] = q[0]; qy[k] = q[1]; qz[k] = q[2];
    s0a[k] = 0.f; s1a[k] = 0.f;
  }

#pragma unroll 2
  for (int nn = 0; nn < chunk; ++nn) {
    float4 p = x1s[nn];
    float d2v[MBLK], arg[MBLK];
#pragma unroll
    for (int k = 0; k < MBLK; ++k) {
      float dx = p.x - qx[k], dy = p.y - qy[k], dz = p.z - qz[k];
      d2v[k] = fmaf(dz, dz, fmaf(dy, dy, dx * dx));
      arg[k] = d2v[k] * c2;
    }
    bool go = true;
    if (SKIP) {
      float amax = arg[0];
#pragma unroll
      for (int k = 1; k < MBLK; ++k) amax = fmaxf(amax, arg[k]);
      go = amax > -126.f;
    }
    if (go) {
#pragma unroll
      for (int k = 0; k < MBLK; ++k) {
        float e  = EXP2(arg[k]);
        float tt = p.w * e;
        s0a[k] += tt;
        s1a[k] = fmaf(tt, SQRTF(d2v[k]), s1a[k]);
      }
    }
  }

  size_t sbase = ((size_t)nsegi * NB + b) * NPTS;
#pragma unroll
  for (int k = 0; k < MBLK; ++k) {
    s0P[sbase + m0 + k * TPB] = s0a[k];
    s1P[sbase + m0 + k * TPB] = s1a[k];
  }
}

// ---------------------------------------------------------------------------
// F kernel: final iteration's cost contribution, parallel over m-chunks,
// atomically accumulated into costbuf. Grid (NPTS/TPB, NB).
// ---------------------------------------------------------------------------
__global__ __launch_bounds__(TPB) void f_kernel(
    const float* __restrict__ s0P, const float* __restrict__ s1P,
    const float* __restrict__ rrbuf, float* __restrict__ costbuf, int nseg)
{
  __shared__ float red[TPB];
  const int b   = blockIdx.y;
  const int tid = threadIdx.x;
  const int m   = blockIdx.x * TPB + tid;
  const int plane = NB * NPTS;
  float s0 = 0.f, s1 = 0.f;
  for (int s = 0; s < nseg; ++s) {
    s0 += s0P[(s * NB + b) * NPTS + m];
    s1 += s1P[(s * NB + b) * NPTS + m];
  }
  float rr    = rrbuf[1 * plane + b * NPTS + m];  // remainR_9 (parity 9&1=1)
  float sumr  = fmaf(rr, s0, EPSC);
  float ratio = fminf(rr * RCPF(sumr), 1.f);
  red[tid] = rr * ratio * s1;
  __syncthreads();
  for (int s = TPB / 2; s > 0; s >>= 1) {
    if (tid < s) red[tid] += red[tid + s];
    __syncthreads();
  }
  if (tid == 0) atomicAdd(costbuf + b, red[0]);
}

__global__ void out_kernel(const float* __restrict__ costbuf,
                           float* __restrict__ out)
{
  int t = threadIdx.x;
  if (t < NB) out[t] = costbuf[t];
}

extern "C" void kernel_launch(void* const* d_in, const int* in_sizes, int n_in,
                              void* d_out, int out_size, void* d_ws, size_t ws_size,
                              hipStream_t stream) {
  const float* x1 = (const float*)d_in[0];
  const float* x2 = (const float*)d_in[1];
  float* out = (float*)d_out;

  const size_t plane = (size_t)NB * NPTS;
  // ws need: dbuf 2*nseg + rsum/s0/s1 nseg each = 5*nseg planes, + lbuf 2 + rrbuf 2 + costbuf
  int nseg = 32;
  while (nseg > 4 &&
         ((size_t)(5 * nseg + 4) * plane + NB) * sizeof(float) > ws_size)
    nseg >>= 1;
  const int chunk = NPTS / nseg;

  float* ws      = (float*)d_ws;
  float* dbuf    = ws;
  float* rsumP   = dbuf  + 2 * nseg * plane;
  float* s0P     = rsumP + nseg * plane;
  float* s1P     = s0P   + nseg * plane;
  float* lbuf    = s1P   + nseg * plane;
  float* rrbuf   = lbuf  + 2 * plane;
  float* costbuf = rrbuf + 2 * plane;

  const double L2E = 1.4426950408889634074;
  const double lv[10] = {-16384.0, -4096.0, -1024.0, -256.0, -64.0,
                         -16.0, -4.0, -1.0, -0.25, 0.0};
  float c2[10];
  for (int i = 0; i < 10; ++i) c2[i] = (float)(lv[i] * L2E);

  dim3 grid(NPTS / (TPB * MBLK), nseg, NB), blk(TPB);

  // A_0 (denom_0 partials), zero costbuf
  ca_kernel<0, true><<<grid, blk, 0, stream>>>(
      x1, x2, dbuf, rsumP, s0P, s1P, rrbuf, costbuf, -1, 0.f, c2[0], nseg, chunk);
  for (int i = 0; i < 10; ++i) {
    if (i <= 2)   // levels -16384,-4096,-1024: whole-group skip actually fires
      b_kernel<true><<<grid, blk, 0, stream>>>(
          x1, x2, dbuf, rsumP, s0P, s1P, lbuf, i, c2[i], nseg, chunk);
    else
      b_kernel<false><<<grid, blk, 0, stream>>>(
          x1, x2, dbuf, rsumP, s0P, s1P, lbuf, i, c2[i], nseg, chunk);
    if (i < 8) {
      if (i <= 1)  // e at level i+1: skip only while i+1 <= 2
        ca_kernel<1, true><<<grid, blk, 0, stream>>>(
            x1, x2, dbuf, rsumP, s0P, s1P, rrbuf, costbuf, i, c2[i], c2[i + 1], nseg, chunk);
      else
        ca_kernel<1, false><<<grid, blk, 0, stream>>>(
            x1, x2, dbuf, rsumP, s0P, s1P, rrbuf, costbuf, i, c2[i], c2[i + 1], nseg, chunk);
    } else if (i == 8) {
      ca_kernel<2, false><<<grid, blk, 0, stream>>>(
          x1, x2, dbuf, rsumP, s0P, s1P, rrbuf, costbuf, 8, c2[8], 0.f, nseg, chunk);
    }
  }
  f_kernel<<<dim3(NPTS / TPB, NB), blk, 0, stream>>>(s0P, s1P, rrbuf, costbuf, nseg);
  out_kernel<<<dim3(1), dim3(64), 0, stream>>>(costbuf, out);
}

// Round 5
// 1034.308 us; speedup vs baseline: 2.2379x; 1.1811x over previous
//
#include <hip/hip_runtime.h>

#define NPTS 4096
#define NB   8
#define TPB  256
#define TPBR 128
#define MBLK 4
#define EPSC 1e-9f

#define EXP2(x)  __builtin_amdgcn_exp2f(x)
#define RCPF(x)  __builtin_amdgcn_rcpf(x)
#define SQRTF(x) __builtin_amdgcn_sqrtf(x)

// ---------------------------------------------------------------------------
// CA kernel: pass C of iter i (rsum[n] = sum_m e_i*u[m]) fused with pass A of
// iter i+1 (denom[n] = sum_m e_{i+1}*rr_{i+1}[m]).  Coordinates staged
// pre-scaled by sc so arg = -(dx^2+dy^2+dz^2).
// MODE 0: A_0 only (u=0, rr=1, zeroes out[]).  MODE 1: e_i = e_{i+1}^4.
// MODE 2: i=8 (level_{i+1}=0 -> denom += rr; sc = scale of level_8 for e_8).
// ---------------------------------------------------------------------------
template<int MODE, bool SKIP, int CHUNK>
__global__ __launch_bounds__(TPB) void ca_kernel(
    const float* __restrict__ x2,
    float* __restrict__ dbufP,          // [NSEG][NB][NPTS] denom_{i+1} partials
    float* __restrict__ rsumP,          // [NSEG][NB][NPTS] rsum_i partials
    const float* __restrict__ x1,
    const float* __restrict__ ubuf,     // [NB][NPTS] u_i
    const float* __restrict__ rrbuf,    // [NB][NPTS] rr_{i+1}
    float* __restrict__ out, float sc)
{
  __shared__ float4 x2s[CHUNK];   // (sc*x, sc*y, sc*z, u)
  __shared__ float  rrs[CHUNK];   // rr_{i+1}

  const int tid = threadIdx.x;
  const int nchunk = blockIdx.x, mseg = blockIdx.y, b = blockIdx.z;
  const int m0 = mseg * CHUNK;

  if (MODE == 0 && nchunk == 0 && mseg == 0 && tid == 0) out[b] = 0.f;

  for (int mm = tid; mm < CHUNK; mm += TPB) {
    int m = m0 + mm;
    const float* q = x2 + ((size_t)b * NPTS + m) * 3;
    float u = 0.f, rrn = 1.f;
    if (MODE >= 1) { u = ubuf[b * NPTS + m]; rrn = rrbuf[b * NPTS + m]; }
    x2s[mm] = make_float4(sc * q[0], sc * q[1], sc * q[2], u);
    rrs[mm] = rrn;
  }
  __syncthreads();

  const int n0 = nchunk * (TPB * MBLK) + tid;
  float px[MBLK], py[MBLK], pz[MBLK], dacc[MBLK], racc[MBLK];
#pragma unroll
  for (int k = 0; k < MBLK; ++k) {
    const float* p = x1 + ((size_t)b * NPTS + n0 + k * TPB) * 3;
    px[k] = sc * p[0]; py[k] = sc * p[1]; pz[k] = sc * p[2];
    dacc[k] = 0.f; racc[k] = 0.f;
  }

#pragma unroll 4
  for (int mm = 0; mm < CHUNK; ++mm) {
    float4 q  = x2s[mm];
    float rrv = rrs[mm];
    float ds2[MBLK];
#pragma unroll
    for (int k = 0; k < MBLK; ++k) {
      float dx = px[k] - q.x, dy = py[k] - q.y, dz = pz[k] - q.z;
      ds2[k] = fmaf(dz, dz, fmaf(dy, dy, dx * dx));   // = -arg
    }
    if (MODE == 2) {
#pragma unroll
      for (int k = 0; k < MBLK; ++k) {
        dacc[k] += rrv;
        float ec = EXP2(-ds2[k]);        // e_8
        racc[k] = fmaf(ec, q.w, racc[k]);
      }
    } else {
      bool go = true;
      if (SKIP) {
        float dmin = ds2[0];
#pragma unroll
        for (int k = 1; k < MBLK; ++k) dmin = fminf(dmin, ds2[k]);
        go = dmin < 126.f;
      }
      if (go) {
#pragma unroll
        for (int k = 0; k < MBLK; ++k) {
          float en = EXP2(-ds2[k]);      // e_{i+1}
          dacc[k] = fmaf(en, rrv, dacc[k]);
          if (MODE == 1) { float e2 = en * en; racc[k] = fmaf(e2 * e2, q.w, racc[k]); }
        }
      }
    }
  }

  size_t base = ((size_t)mseg * NB + b) * NPTS;
#pragma unroll
  for (int k = 0; k < MBLK; ++k) {
    dbufP[base + n0 + k * TPB] = dacc[k];
    if (MODE >= 1) rsumP[base + n0 + k * TPB] = racc[k];
  }
}

// ---------------------------------------------------------------------------
// B kernel: s0[m] = sum_n a*e_i, s1[m] = sum_n a*e_i*dist.  Coordinates staged
// pre-scaled by sc; s1 accumulated in scaled distance units, de-scaled by
// inv_s at writeout.  LVL0: i=9 (e=1, unscaled coords, no exp).
// ---------------------------------------------------------------------------
template<int LVL0, bool SKIP, int CHUNK>
__global__ __launch_bounds__(TPB) void b_kernel(
    const float* __restrict__ x1,
    const float* __restrict__ abuf,     // [NB][NPTS] a_i
    float* __restrict__ s0P, float* __restrict__ s1P,  // [NSEG][NB][NPTS]
    const float* __restrict__ x2, float sc, float inv_s)
{
  __shared__ float4 x1s[CHUNK];   // (sc*x, sc*y, sc*z, a)

  const int tid = threadIdx.x;
  const int mchunk = blockIdx.x, nsegi = blockIdx.y, b = blockIdx.z;
  const int n0 = nsegi * CHUNK;

  for (int nn = tid; nn < CHUNK; nn += TPB) {
    int n = n0 + nn;
    const float* p = x1 + ((size_t)b * NPTS + n) * 3;
    float a = abuf[b * NPTS + n];
    x1s[nn] = make_float4(sc * p[0], sc * p[1], sc * p[2], a);
  }
  __syncthreads();

  const int m0 = mchunk * (TPB * MBLK) + tid;
  float qx[MBLK], qy[MBLK], qz[MBLK], s0a[MBLK], s1a[MBLK];
#pragma unroll
  for (int k = 0; k < MBLK; ++k) {
    const float* q = x2 + ((size_t)b * NPTS + m0 + k * TPB) * 3;
    qx[k] = sc * q[0]; qy[k] = sc * q[1]; qz[k] = sc * q[2];
    s0a[k] = 0.f; s1a[k] = 0.f;
  }

#pragma unroll 4
  for (int nn = 0; nn < CHUNK; ++nn) {
    float4 p = x1s[nn];
    float ds2[MBLK];
#pragma unroll
    for (int k = 0; k < MBLK; ++k) {
      float dx = p.x - qx[k], dy = p.y - qy[k], dz = p.z - qz[k];
      ds2[k] = fmaf(dz, dz, fmaf(dy, dy, dx * dx));
    }
    if (LVL0) {
#pragma unroll
      for (int k = 0; k < MBLK; ++k) {
        s0a[k] += p.w;
        s1a[k] = fmaf(p.w, SQRTF(ds2[k]), s1a[k]);
      }
    } else {
      bool go = true;
      if (SKIP) {
        float dmin = ds2[0];
#pragma unroll
        for (int k = 1; k < MBLK; ++k) dmin = fminf(dmin, ds2[k]);
        go = dmin < 126.f;
      }
      if (go) {
#pragma unroll
        for (int k = 0; k < MBLK; ++k) {
          float e  = EXP2(-ds2[k]);
          float tt = p.w * e;
          s0a[k] += tt;
          s1a[k] = fmaf(tt, SQRTF(ds2[k]), s1a[k]);  // scaled dist
        }
      }
    }
  }

  size_t base = ((size_t)nsegi * NB + b) * NPTS;
#pragma unroll
  for (int k = 0; k < MBLK; ++k) {
    s0P[base + m0 + k * TPB] = s0a[k];
    s1P[base + m0 + k * TPB] = s1a[k] * inv_s;
  }
}

// ---------------------------------------------------------------------------
// R1: n-side fixup before B_i.  denom_i = sum dbufP; rl_i via recurrence using
// lbuf (rl_{i-1}), dtot (denom_{i-1}), rsumP (rsum_{i-1}); a_i = rl/(denom+eps).
// ---------------------------------------------------------------------------
template<int NSEG>
__global__ __launch_bounds__(TPBR) void r1_kernel(
    const float* __restrict__ dbufP, const float* __restrict__ rsumP,
    float* __restrict__ lbuf, float* __restrict__ dtot,
    float* __restrict__ abuf, int iter)
{
  const int idx = blockIdx.x * TPBR + threadIdx.x;   // over NB*NPTS
  const int b = idx >> 12, n = idx & (NPTS - 1);
  const int off = b * NPTS + n;

  float dnew = 0.f;
#pragma unroll
  for (int s = 0; s < NSEG; ++s) dnew += dbufP[((size_t)s * NB + b) * NPTS + n];

  float rl;
  if (iter == 0) {
    rl = 1.f;
  } else {
    float rlp = lbuf[off];
    float ap  = rlp * RCPF(dtot[off] + EPSC);
    float rs = 0.f;
#pragma unroll
    for (int s = 0; s < NSEG; ++s) rs += rsumP[((size_t)s * NB + b) * NPTS + n];
    rl = fmaxf(rlp - ap * rs, 0.f);
  }
  lbuf[off] = rl;
  dtot[off] = dnew;
  abuf[off] = rl * RCPF(dnew + EPSC);
}

// ---------------------------------------------------------------------------
// R2: m-side fixup after B_i.  s0 = sum s0P; u = rr*min(rr/(rr*s0+eps),1);
// rr <- max(rr-u*s0,0) in place; cost += sum_m u*s1 (atomic into out[b]).
// LAST (i=9): cost only.
// ---------------------------------------------------------------------------
template<int NSEG, bool LAST>
__global__ __launch_bounds__(TPBR) void r2_kernel(
    const float* __restrict__ s0P, const float* __restrict__ s1P,
    float* __restrict__ ubuf, float* __restrict__ rrbuf,
    float* __restrict__ out, int iter)
{
  __shared__ float red[TPBR];
  const int idx = blockIdx.x * TPBR + threadIdx.x;
  const int b = idx >> 12, m = idx & (NPTS - 1);
  const int off = b * NPTS + m;

  float s0 = 0.f, s1 = 0.f;
#pragma unroll
  for (int s = 0; s < NSEG; ++s) {
    s0 += s0P[((size_t)s * NB + b) * NPTS + m];
    s1 += s1P[((size_t)s * NB + b) * NPTS + m];
  }
  float rr    = (iter == 0) ? 1.f : rrbuf[off];
  float sumr  = fmaf(rr, s0, EPSC);
  float ratio = fminf(rr * RCPF(sumr), 1.f);
  float u     = rr * ratio;
  if (!LAST) {
    ubuf[off]  = u;
    rrbuf[off] = fmaxf(rr - u * s0, 0.f);
  }

  red[threadIdx.x] = u * s1;
  __syncthreads();
  for (int s = TPBR / 2; s > 0; s >>= 1) {
    if (threadIdx.x < s) red[threadIdx.x] += red[threadIdx.x + s];
    __syncthreads();
  }
  if (threadIdx.x == 0) atomicAdd(out + b, red[0]);
}

// ---------------------------------------------------------------------------
template<int NSEG>
static void run_all(const float* x1, const float* x2, float* out, float* ws,
                    hipStream_t stream)
{
  constexpr int CHUNK = NPTS / NSEG;
  const size_t plane = (size_t)NB * NPTS;

  float* dbufP = ws;
  float* rsumP = dbufP + (size_t)NSEG * plane;
  float* s0P   = rsumP + (size_t)NSEG * plane;
  float* s1P   = s0P   + (size_t)NSEG * plane;
  float* dtot  = s1P   + (size_t)NSEG * plane;
  float* lbuf  = dtot  + plane;
  float* abuf  = lbuf  + plane;
  float* ubuf  = abuf  + plane;
  float* rrbuf = ubuf  + plane;

  const double L2E = 1.4426950408889634074;
  const double lv[10] = {-16384.0, -4096.0, -1024.0, -256.0, -64.0,
                         -16.0, -4.0, -1.0, -0.25, 0.0};
  float scl[10], inv_s[10];
  for (int i = 0; i < 10; ++i) {
    double c2 = lv[i] * L2E;                 // <= 0
    scl[i]   = (i == 9) ? 1.f : (float)sqrt(-c2);
    inv_s[i] = (i == 9) ? 1.f : (float)(1.0 / sqrt(-c2));
  }

  dim3 gmain(NPTS / (TPB * MBLK), NSEG, NB), bmain(TPB);
  dim3 gr(NPTS * NB / TPBR), br(TPBR);

  // A_0: denom_0 partials (e at level j=7), zero out[]
  ca_kernel<0, true, CHUNK><<<gmain, bmain, 0, stream>>>(
      x2, dbufP, rsumP, x1, ubuf, rrbuf, out, scl[0]);

  for (int i = 0; i < 10; ++i) {
    r1_kernel<NSEG><<<gr, br, 0, stream>>>(dbufP, rsumP, lbuf, dtot, abuf, i);

    if (i <= 2)
      b_kernel<0, true, CHUNK><<<gmain, bmain, 0, stream>>>(
          x1, abuf, s0P, s1P, x2, scl[i], inv_s[i]);
    else if (i <= 8)
      b_kernel<0, false, CHUNK><<<gmain, bmain, 0, stream>>>(
          x1, abuf, s0P, s1P, x2, scl[i], inv_s[i]);
    else
      b_kernel<1, false, CHUNK><<<gmain, bmain, 0, stream>>>(
          x1, abuf, s0P, s1P, x2, 1.f, 1.f);

    if (i < 9)
      r2_kernel<NSEG, false><<<gr, br, 0, stream>>>(s0P, s1P, ubuf, rrbuf, out, i);
    else
      r2_kernel<NSEG, true><<<gr, br, 0, stream>>>(s0P, s1P, ubuf, rrbuf, out, i);

    if (i <= 7) {
      if (i <= 1)
        ca_kernel<1, true, CHUNK><<<gmain, bmain, 0, stream>>>(
            x2, dbufP, rsumP, x1, ubuf, rrbuf, out, scl[i + 1]);
      else
        ca_kernel<1, false, CHUNK><<<gmain, bmain, 0, stream>>>(
            x2, dbufP, rsumP, x1, ubuf, rrbuf, out, scl[i + 1]);
    } else if (i == 8) {
      ca_kernel<2, false, CHUNK><<<gmain, bmain, 0, stream>>>(
          x2, dbufP, rsumP, x1, ubuf, rrbuf, out, scl[8]);
    }
  }
}

extern "C" void kernel_launch(void* const* d_in, const int* in_sizes, int n_in,
                              void* d_out, int out_size, void* d_ws, size_t ws_size,
                              hipStream_t stream) {
  const float* x1 = (const float*)d_in[0];
  const float* x2 = (const float*)d_in[1];
  float* out = (float*)d_out;
  float* ws  = (float*)d_ws;

  const size_t plane = (size_t)NB * NPTS;
  auto need = [&](int nseg) {
    return ((size_t)(4 * nseg + 5) * plane) * sizeof(float);
  };

  if (ws_size >= need(64))      run_all<64>(x1, x2, out, ws, stream);
  else if (ws_size >= need(32)) run_all<32>(x1, x2, out, ws, stream);
  else                          run_all<16>(x1, x2, out, ws, stream);
}

// Round 6
// 989.794 us; speedup vs baseline: 2.3386x; 1.0450x over previous
//
#include <hip/hip_runtime.h>

#define NPTS 4096
#define NB   8
#define TPB  256
#define TPBR 128
#define MBLK 4
#define EPSC 1e-9f

#define EXP2(x)  __builtin_amdgcn_exp2f(x)
#define RCPF(x)  __builtin_amdgcn_rcpf(x)
#define SQRTF(x) __builtin_amdgcn_sqrtf(x)

// ---------------------------------------------------------------------------
// Morton bucket sort (4 bits/axis, 4096 buckets) per (set, batch).
// ANY permutation is exactly correct (cost is a set-pairwise sum); sorting
// only improves wave-group skip coherence. Outputs packed float4 arrays.
// ---------------------------------------------------------------------------
__global__ __launch_bounds__(TPB) void sort_kernel(
    const float* __restrict__ x1, const float* __restrict__ x2,
    float4* __restrict__ x1p, float4* __restrict__ x2p)
{
  __shared__ unsigned int   hist[4096];
  __shared__ unsigned short codes[4096];
  __shared__ unsigned int   part[TPB];

  const int set = blockIdx.x, b = blockIdx.y;
  const float* src = set ? x2 : x1;
  float4* dst = set ? x2p : x1p;
  const int tid = threadIdx.x;

  for (int i = tid; i < 4096; i += TPB) hist[i] = 0;
  __syncthreads();

  for (int j = 0; j < NPTS / TPB; ++j) {
    int n = j * TPB + tid;
    const float* p = src + ((size_t)b * NPTS + n) * 3;
    float x = p[0], y = p[1], z = p[2];
    int qx = min(max((int)((x + 4.f) * 2.f), 0), 15);
    int qy = min(max((int)((y + 4.f) * 2.f), 0), 15);
    int qz = min(max((int)((z + 4.f) * 2.f), 0), 15);
    auto ex = [](int v) {
      return (v & 1) | ((v & 2) << 2) | ((v & 4) << 4) | ((v & 8) << 6);
    };
    int code = ex(qx) | (ex(qy) << 1) | (ex(qz) << 2);
    codes[n] = (unsigned short)code;
    atomicAdd(&hist[code], 1u);
  }
  __syncthreads();

  // exclusive scan of hist
  unsigned int loc[16], s = 0;
#pragma unroll
  for (int j = 0; j < 16; ++j) { loc[j] = s; s += hist[tid * 16 + j]; }
  part[tid] = s;
  __syncthreads();
  if (tid == 0) {
    unsigned int run = 0;
    for (int t = 0; t < TPB; ++t) { unsigned int v = part[t]; part[t] = run; run += v; }
  }
  __syncthreads();
  {
    unsigned int base = part[tid];
#pragma unroll
    for (int j = 0; j < 16; ++j) hist[tid * 16 + j] = base + loc[j];
  }
  __syncthreads();

  for (int j = 0; j < NPTS / TPB; ++j) {
    int n = j * TPB + tid;
    const float* p = src + ((size_t)b * NPTS + n) * 3;
    float x = p[0], y = p[1], z = p[2];
    unsigned int pos = atomicAdd(&hist[codes[n]], 1u);
    dst[(size_t)b * NPTS + pos] = make_float4(x, y, z, 0.f);
  }
}

// ---------------------------------------------------------------------------
// CA kernel: pass C of iter i (rsum[n] = sum_m e_i*u[m]) fused with pass A of
// iter i+1 (denom[n] = sum_m e_{i+1}*rr_{i+1}[m]).  Dot-product form:
// staged m-side float4 = (-2*sc*x, -2*sc*y, -2*sc*z, |sc*q|^2); owned n-side
// holds sc-scaled coords + |sc*p|^2.  ds2 = np+nq-2p.q (scaled).
// MODE 0: A_0 only (u=0, rr=1, zeroes out[]).  MODE 1: e_i = e_{i+1}^4.
// MODE 2: i=8 (level 0 for A -> denom += rr; e_8 for C).
// Each lane owns MBLK CONTIGUOUS sorted points (skip-group coherence).
// ---------------------------------------------------------------------------
template<int MODE, bool SKIP, int CHUNK>
__global__ __launch_bounds__(TPB) void ca_kernel(
    const float4* __restrict__ x2p, const float4* __restrict__ x1p,
    const float2* __restrict__ urP,
    float* __restrict__ dbufP, float* __restrict__ rsumP,
    float* __restrict__ out, float sc)
{
  __shared__ float4 x2s[CHUNK];
  __shared__ float2 urs[CHUNK];

  const int tid = threadIdx.x;
  const int nchunk = blockIdx.x, mseg = blockIdx.y, b = blockIdx.z;

  if (MODE == 0 && nchunk == 0 && mseg == 0 && tid == 0) out[b] = 0.f;

  for (int mm = tid; mm < CHUNK; mm += TPB) {
    int m = mseg * CHUNK + mm;
    float4 q = x2p[(size_t)b * NPTS + m];
    float sx = sc * q.x, sy = sc * q.y, sz = sc * q.z;
    float nq = fmaf(sz, sz, fmaf(sy, sy, sx * sx));
    x2s[mm] = make_float4(-2.f * sx, -2.f * sy, -2.f * sz, nq);
    urs[mm] = (MODE == 0) ? make_float2(0.f, 1.f) : urP[(size_t)b * NPTS + m];
  }
  __syncthreads();

  const int n0 = nchunk * (TPB * MBLK) + tid * MBLK;
  float px[MBLK], py[MBLK], pz[MBLK], np[MBLK], dacc[MBLK], racc[MBLK];
#pragma unroll
  for (int k = 0; k < MBLK; ++k) {
    float4 p = x1p[(size_t)b * NPTS + n0 + k];
    px[k] = sc * p.x; py[k] = sc * p.y; pz[k] = sc * p.z;
    np[k] = fmaf(pz[k], pz[k], fmaf(py[k], py[k], px[k] * px[k]));
    dacc[k] = 0.f; racc[k] = 0.f;
  }

#pragma unroll 4
  for (int mm = 0; mm < CHUNK; ++mm) {
    float4 q = x2s[mm];
    float2 ur = urs[mm];
    float ds2[MBLK];
#pragma unroll
    for (int k = 0; k < MBLK; ++k)
      ds2[k] = fmaf(q.x, px[k], fmaf(q.y, py[k], fmaf(q.z, pz[k], np[k] + q.w)));
    if (MODE == 2) {
#pragma unroll
      for (int k = 0; k < MBLK; ++k) {
        dacc[k] += ur.y;
        racc[k] = fmaf(EXP2(-ds2[k]), ur.x, racc[k]);
      }
    } else {
      bool go = true;
      if (SKIP) {
        float dmin = fminf(fminf(ds2[0], ds2[1]), fminf(ds2[2], ds2[3]));
        go = dmin < 126.f;
      }
      if (go) {
#pragma unroll
        for (int k = 0; k < MBLK; ++k) {
          float en = EXP2(-ds2[k]);
          dacc[k] = fmaf(en, ur.y, dacc[k]);
          if (MODE == 1) { float e2 = en * en; racc[k] = fmaf(e2 * e2, ur.x, racc[k]); }
        }
      }
    }
  }

  size_t base = ((size_t)mseg * NB + b) * NPTS + n0;
  *(float4*)&dbufP[base] = make_float4(dacc[0], dacc[1], dacc[2], dacc[3]);
  if (MODE >= 1)
    *(float4*)&rsumP[base] = make_float4(racc[0], racc[1], racc[2], racc[3]);
}

// ---------------------------------------------------------------------------
// B kernel: s0[m] = sum_n a*e_i, s1[m] = sum_n a*e_i*dist (de-scaled once).
// LVL0: i=9 (e=1, sc=1).  Same dot-product staging, n-side staged.
// ---------------------------------------------------------------------------
template<int LVL0, bool SKIP, int CHUNK>
__global__ __launch_bounds__(TPB) void b_kernel(
    const float4* __restrict__ x1p, const float* __restrict__ abuf,
    const float4* __restrict__ x2p,
    float* __restrict__ s0P, float* __restrict__ s1P,
    float sc, float inv_s)
{
  __shared__ float4 x1s[CHUNK];
  __shared__ float  as_[CHUNK];

  const int tid = threadIdx.x;
  const int mchunk = blockIdx.x, nsegi = blockIdx.y, b = blockIdx.z;

  for (int nn = tid; nn < CHUNK; nn += TPB) {
    int n = nsegi * CHUNK + nn;
    float4 p = x1p[(size_t)b * NPTS + n];
    float sx = sc * p.x, sy = sc * p.y, sz = sc * p.z;
    float npv = fmaf(sz, sz, fmaf(sy, sy, sx * sx));
    x1s[nn] = make_float4(-2.f * sx, -2.f * sy, -2.f * sz, npv);
    as_[nn] = abuf[(size_t)b * NPTS + n];
  }
  __syncthreads();

  const int m0 = mchunk * (TPB * MBLK) + tid * MBLK;
  float qx[MBLK], qy[MBLK], qz[MBLK], nq[MBLK], s0a[MBLK], s1a[MBLK];
#pragma unroll
  for (int k = 0; k < MBLK; ++k) {
    float4 q = x2p[(size_t)b * NPTS + m0 + k];
    qx[k] = sc * q.x; qy[k] = sc * q.y; qz[k] = sc * q.z;
    nq[k] = fmaf(qz[k], qz[k], fmaf(qy[k], qy[k], qx[k] * qx[k]));
    s0a[k] = 0.f; s1a[k] = 0.f;
  }

#pragma unroll 4
  for (int nn = 0; nn < CHUNK; ++nn) {
    float4 p = x1s[nn];
    float av = as_[nn];
    float ds2[MBLK];
#pragma unroll
    for (int k = 0; k < MBLK; ++k)
      ds2[k] = fmaf(p.x, qx[k], fmaf(p.y, qy[k], fmaf(p.z, qz[k], nq[k] + p.w)));
    if (LVL0) {
#pragma unroll
      for (int k = 0; k < MBLK; ++k) {
        s0a[k] += av;
        s1a[k] = fmaf(av, SQRTF(__builtin_fabsf(ds2[k])), s1a[k]);
      }
    } else {
      bool go = true;
      if (SKIP) {
        float dmin = fminf(fminf(ds2[0], ds2[1]), fminf(ds2[2], ds2[3]));
        go = dmin < 126.f;
      }
      if (go) {
#pragma unroll
        for (int k = 0; k < MBLK; ++k) {
          float tt = av * EXP2(-ds2[k]);
          s0a[k] += tt;
          s1a[k] = fmaf(tt, SQRTF(__builtin_fabsf(ds2[k])), s1a[k]);
        }
      }
    }
  }

  size_t base = ((size_t)nsegi * NB + b) * NPTS + m0;
  *(float4*)&s0P[base] = make_float4(s0a[0], s0a[1], s0a[2], s0a[3]);
  *(float4*)&s1P[base] = make_float4(s1a[0] * inv_s, s1a[1] * inv_s,
                                     s1a[2] * inv_s, s1a[3] * inv_s);
}

// ---------------------------------------------------------------------------
// R1: n-side fixup. denom_i = sum dbufP; rl_i recurrence; a_i = rl/(denom+eps).
// ---------------------------------------------------------------------------
template<int NSEG>
__global__ __launch_bounds__(TPBR) void r1_kernel(
    const float* __restrict__ dbufP, const float* __restrict__ rsumP,
    float* __restrict__ lbuf, float* __restrict__ dtot,
    float* __restrict__ abuf, int iter)
{
  const int idx = blockIdx.x * TPBR + threadIdx.x;
  const int b = idx >> 12, n = idx & (NPTS - 1);
  const int off = b * NPTS + n;

  float dnew = 0.f;
#pragma unroll
  for (int s = 0; s < NSEG; ++s) dnew += dbufP[((size_t)s * NB + b) * NPTS + n];

  float rl;
  if (iter == 0) {
    rl = 1.f;
  } else {
    float rlp = lbuf[off];
    float ap  = rlp * RCPF(dtot[off] + EPSC);
    float rs = 0.f;
#pragma unroll
    for (int s = 0; s < NSEG; ++s) rs += rsumP[((size_t)s * NB + b) * NPTS + n];
    rl = fmaxf(rlp - ap * rs, 0.f);
  }
  lbuf[off] = rl;
  dtot[off] = dnew;
  abuf[off] = rl * RCPF(dnew + EPSC);
}

// ---------------------------------------------------------------------------
// R2: m-side fixup. s0 = sum s0P; u = rr*min(rr/(rr*s0+eps),1); rr update
// in place (urbuf float2 = (u, rr)); cost partial atomically into out[b].
// ---------------------------------------------------------------------------
template<int NSEG, bool LAST>
__global__ __launch_bounds__(TPBR) void r2_kernel(
    const float* __restrict__ s0P, const float* __restrict__ s1P,
    float2* __restrict__ urbuf, float* __restrict__ out, int iter)
{
  __shared__ float red[TPBR];
  const int idx = blockIdx.x * TPBR + threadIdx.x;
  const int b = idx >> 12, m = idx & (NPTS - 1);
  const int off = b * NPTS + m;

  float s0 = 0.f, s1 = 0.f;
#pragma unroll
  for (int s = 0; s < NSEG; ++s) {
    s0 += s0P[((size_t)s * NB + b) * NPTS + m];
    s1 += s1P[((size_t)s * NB + b) * NPTS + m];
  }
  float rr    = (iter == 0) ? 1.f : urbuf[off].y;
  float sumr  = fmaf(rr, s0, EPSC);
  float ratio = fminf(rr * RCPF(sumr), 1.f);
  float u     = rr * ratio;
  if (!LAST) urbuf[off] = make_float2(u, fmaxf(rr - u * s0, 0.f));

  red[threadIdx.x] = u * s1;
  __syncthreads();
  for (int s = TPBR / 2; s > 0; s >>= 1) {
    if (threadIdx.x < s) red[threadIdx.x] += red[threadIdx.x + s];
    __syncthreads();
  }
  if (threadIdx.x == 0) atomicAdd(out + b, red[0]);
}

// ---------------------------------------------------------------------------
template<int NSEG>
static void run_all(const float* x1, const float* x2, float* out, float* ws,
                    hipStream_t stream)
{
  constexpr int CHUNK = NPTS / NSEG;
  const size_t plane = (size_t)NB * NPTS;

  // {dbufP,rsumP} and {s0P,s1P} have disjoint live ranges -> alias.
  float*  bufA = ws;                       // NSEG planes
  float*  bufB = bufA + (size_t)NSEG * plane;
  float4* x1p  = (float4*)(bufB + (size_t)NSEG * plane);  // 4 planes
  float4* x2p  = x1p + plane;                             // 4 planes
  float*  dtot = (float*)(x2p + plane);
  float*  lbuf = dtot + plane;
  float*  abuf = lbuf + plane;
  float2* urbuf = (float2*)(abuf + plane);                // 2 planes

  const double L2E = 1.4426950408889634074;
  const double lv[10] = {-16384.0, -4096.0, -1024.0, -256.0, -64.0,
                         -16.0, -4.0, -1.0, -0.25, 0.0};
  float scl[10], inv_s[10];
  for (int i = 0; i < 10; ++i) {
    double c2 = lv[i] * L2E;
    scl[i]   = (i == 9) ? 1.f : (float)sqrt(-c2);
    inv_s[i] = (i == 9) ? 1.f : (float)(1.0 / sqrt(-c2));
  }

  dim3 gmain(NPTS / (TPB * MBLK), NSEG, NB), bmain(TPB);
  dim3 gr(NPTS * NB / TPBR), br(TPBR);

  sort_kernel<<<dim3(2, NB), bmain, 0, stream>>>(x1, x2, x1p, x2p);

  // A_0: denom_0 partials (level -16384), zero out[]
  ca_kernel<0, true, CHUNK><<<gmain, bmain, 0, stream>>>(
      x2p, x1p, urbuf, bufA, bufB, out, scl[0]);

  for (int i = 0; i < 10; ++i) {
    r1_kernel<NSEG><<<gr, br, 0, stream>>>(bufA, bufB, lbuf, dtot, abuf, i);

    if (i <= 4)
      b_kernel<0, true, CHUNK><<<gmain, bmain, 0, stream>>>(
          x1p, abuf, x2p, bufA, bufB, scl[i], inv_s[i]);
    else if (i <= 8)
      b_kernel<0, false, CHUNK><<<gmain, bmain, 0, stream>>>(
          x1p, abuf, x2p, bufA, bufB, scl[i], inv_s[i]);
    else
      b_kernel<1, false, CHUNK><<<gmain, bmain, 0, stream>>>(
          x1p, abuf, x2p, bufA, bufB, 1.f, 1.f);

    if (i < 9)
      r2_kernel<NSEG, false><<<gr, br, 0, stream>>>(bufA, bufB, urbuf, out, i);
    else
      r2_kernel<NSEG, true><<<gr, br, 0, stream>>>(bufA, bufB, urbuf, out, i);

    if (i <= 3)
      ca_kernel<1, true, CHUNK><<<gmain, bmain, 0, stream>>>(
          x2p, x1p, urbuf, bufA, bufB, out, scl[i + 1]);
    else if (i <= 7)
      ca_kernel<1, false, CHUNK><<<gmain, bmain, 0, stream>>>(
          x2p, x1p, urbuf, bufA, bufB, out, scl[i + 1]);
    else if (i == 8)
      ca_kernel<2, false, CHUNK><<<gmain, bmain, 0, stream>>>(
          x2p, x1p, urbuf, bufA, bufB, out, scl[8]);
  }
}

extern "C" void kernel_launch(void* const* d_in, const int* in_sizes, int n_in,
                              void* d_out, int out_size, void* d_ws, size_t ws_size,
                              hipStream_t stream) {
  const float* x1 = (const float*)d_in[0];
  const float* x2 = (const float*)d_in[1];
  float* out = (float*)d_out;
  float* ws  = (float*)d_ws;

  const size_t plane = (size_t)NB * NPTS;
  auto need = [&](int nseg) {
    return (size_t)(2 * nseg + 13) * plane * sizeof(float);
  };

  if (ws_size >= need(64))      run_all<64>(x1, x2, out, ws, stream);
  else if (ws_size >= need(32)) run_all<32>(x1, x2, out, ws, stream);
  else                          run_all<16>(x1, x2, out, ws, stream);
}